// Round 6
// baseline (1057.915 us; speedup 1.0000x reference)
//
#include <hip/hip_runtime.h>

// FAPBlur: foveated adaptive gaussian blur.
// bin(p) via integer d^2 thresholds (monotone map d2 -> sigma -> bin).
// Per 32x128 tile: loop over bins present, restricted to the row-groups that
// contain each bin: hblur (global->LDS) then vblur (LDS->regs), masked merge.
// R4/R5/R6: bin-15 fully unrolled paths, row-range restriction, XCD swizzle,
// bins computed inline (no bins buffer), launch_bounds(512,4).

#define TW 32
#define TH 128
#define HSTRIDE 36             // 36 mod 32 = 4 -> bank spread
#define HROWS 196              // TH + 2*RMAX (RMAX=34)

// ---------------- kernel 0: thresholds + gaussian weight tables ----------------
__global__ void precompute_kernel(float* __restrict__ wtabH, float* __restrict__ wtabV,
                                  int* __restrict__ thr) {
    int t = threadIdx.x;
    if (t >= 1 && t < 16) {
        // minimal integer d2 with sigma_px(d2) > 0.75*t  (weakly monotone)
        float edge = 0.75f * (float)t;
        int lo = 0, hi = 2093059;
        while (lo < hi) {
            int mid = (lo + hi) >> 1;
            float d  = sqrtf((float)mid);
            float dm = d * 0.07f;              // PIXEL_MM
            float a  = 1.5f * (dm - 18.2f);    // ALPHA*(d_mm - MU)
            double p = 1.0 / (1.0 + exp((double)(-a)));
            float sm = 0.84f * (float)p;       // BETA
            float v  = fminf(fmaxf(sm / 0.07f, 0.0f), 12.0f);
            if (v > edge) hi = mid; else lo = mid + 1;
        }
        thr[t] = lo;
    }
    if (t >= 32 && t < 48) {
        int q = t - 32;
        double s = 0.75 * ((double)q + 0.5);
        int R = (9 * q + 4) >> 2;              // == int(3*s)
        int ks = 2 * R + 1;
        int lead = (-R) & 3;
        double sum = 0.0;
        for (int j = 0; j < ks; j++) {
            double ax = (double)(j - R);
            sum += exp(-0.5 * (ax / s) * (ax / s));
        }
        for (int jj = 0; jj < 72; jj++) {
            int j = jj - lead;
            float w = 0.f;
            if (j >= 0 && j < ks) {
                double ax = (double)(j - R);
                w = (float)(exp(-0.5 * (ax / s) * (ax / s)) / sum);
            }
            wtabH[q * 72 + jj] = w;            // lead-shifted for aligned float4
        }
        for (int jj = 0; jj < 88; jj++) {
            int j = jj - 7;
            float w = 0.f;
            if (j >= 0 && j < ks) {
                double ax = (double)(j - R);
                w = (float)(exp(-0.5 * (ax / s) * (ax / s)) / sum);
            }
            wtabV[q * 88 + jj] = w;            // 7-lead pad: wvp[7+s-r] always valid
        }
    }
}

// ---------------- hblur row: 8 cols, sliding float4 window ----------------
#define HB_STEP(jb_) { \
    float4 wq = *(const float4*)(wh + (jb_)); \
    float4 q2 = L4(A + (jb_) + 8); \
    a0 += wq.x*q0.x + wq.y*q0.y + wq.z*q0.z + wq.w*q0.w; \
    a1 += wq.x*q0.y + wq.y*q0.z + wq.z*q0.w + wq.w*q1.x; \
    a2 += wq.x*q0.z + wq.y*q0.w + wq.z*q1.x + wq.w*q1.y; \
    a3 += wq.x*q0.w + wq.y*q1.x + wq.z*q1.y + wq.w*q1.z; \
    a4 += wq.x*q1.x + wq.y*q1.y + wq.z*q1.z + wq.w*q1.w; \
    a5 += wq.x*q1.y + wq.y*q1.z + wq.z*q1.w + wq.w*q2.x; \
    a6 += wq.x*q1.z + wq.y*q1.w + wq.z*q2.x + wq.w*q2.y; \
    a7 += wq.x*q1.w + wq.y*q2.x + wq.z*q2.y + wq.w*q2.z; \
    q0 = q1; q1 = q2; }

template<int KSE, bool EDGE>
__device__ __forceinline__ void hblur_row(const float* __restrict__ xr, float* hd,
                                          const float* __restrict__ wh, int A, int kseRT) {
    auto L4 = [&](int idx) -> float4 {
        if constexpr (EDGE) {
            bool v = (unsigned)idx < 1021u;      // aligned float4 fully in [0,1024)
            const float* p = xr + (v ? idx : 0);
            float4 r = *(const float4*)p;
            if (!v) { r.x = 0.f; r.y = 0.f; r.z = 0.f; r.w = 0.f; }
            return r;
        } else {
            return *(const float4*)(xr + idx);
        }
    };
    float a0 = 0.f, a1 = 0.f, a2 = 0.f, a3 = 0.f, a4 = 0.f, a5 = 0.f, a6 = 0.f, a7 = 0.f;
    float4 q0 = L4(A), q1 = L4(A + 4);
    if constexpr (KSE != 0) {
#pragma unroll
        for (int jb = 0; jb < KSE; jb += 4) HB_STEP(jb)
    } else {
        for (int jb = 0; jb < kseRT; jb += 4) HB_STEP(jb)
    }
    *(float4*)hd       = make_float4(a0, a1, a2, a3);
    *(float4*)(hd + 4) = make_float4(a4, a5, a6, a7);
}

template<int KSE>
__device__ __forceinline__ void hblur_pass(const float* __restrict__ xp, float* hbuf,
                                           const float* __restrict__ wh, int x0, int y0,
                                           int rbase, int rend, int R, int lead, int kseRT,
                                           int ht, int hg, bool edgeX) {
    for (int h = rbase + ht; h < rend; h += 128) {
        int gy = y0 + h - R;                       // image row for hbuf row h
        float* hd = &hbuf[h * HSTRIDE + hg];
        if ((unsigned)gy < 1024u) {
            const float* xr = xp + ((size_t)gy << 10);
            int A = x0 + hg - R - lead;            // 4-aligned
            if (edgeX) hblur_row<KSE, true>(xr, hd, wh, A, kseRT);
            else       hblur_row<KSE, false>(xr, hd, wh, A, kseRT);
        } else {
            *(float4*)hd       = make_float4(0.f, 0.f, 0.f, 0.f);
            *(float4*)(hd + 4) = make_float4(0.f, 0.f, 0.f, 0.f);
        }
    }
}

// ---------------- vblur: 8 consecutive rows/thread, streaming ----------------
#define VB_BODY(s_) { \
    float v = hb[(s_) * HSTRIDE]; \
    a[0] += wvp[7 + (s_)] * v; \
    a[1] += wvp[6 + (s_)] * v; \
    a[2] += wvp[5 + (s_)] * v; \
    a[3] += wvp[4 + (s_)] * v; \
    a[4] += wvp[3 + (s_)] * v; \
    a[5] += wvp[2 + (s_)] * v; \
    a[6] += wvp[1 + (s_)] * v; \
    a[7] += wvp[0 + (s_)] * v; }

template<int NS>
__device__ __forceinline__ void vblur_pass(const float* hb, const float* __restrict__ wvp,
                                           int nsRT, float a[8]) {
    if constexpr (NS != 0) {
#pragma unroll
        for (int s = 0; s < NS; s++) VB_BODY(s)
    } else {
        for (int s = 0; s < nsRT; s++) VB_BODY(s)
    }
}

// ---------------- main tile kernel ----------------
__global__ __launch_bounds__(512, 4) void tile_kernel(const float* __restrict__ x,
                                                      const int* __restrict__ fix,
                                                      const int* __restrict__ thr,
                                                      const float* __restrict__ wtabH,
                                                      const float* __restrict__ wtabV,
                                                      float* __restrict__ out) {
    __shared__ __align__(16) float hbuf[HROWS * HSTRIDE];  // 28,224 B
    __shared__ unsigned int tmask[512];
    __shared__ unsigned int gm[16];
    __shared__ unsigned int binrows[16];

    int blk = blockIdx.x;
    int swz = (blk & 7) * 768 + (blk >> 3);   // XCD-contiguous chunks (6144 = 8*768)
    int tx = swz & 31;
    int ty = (swz >> 5) & 7;
    int bc = swz >> 8;                        // 0..23 = b*3 + ch
    const size_t plane = (size_t)bc << 20;
    const float* xp = x + plane;
    float* op = out + plane;
    int x0 = tx << 5, y0 = ty << 7;
    int tid = threadIdx.x;

    int c  = tid & 31;            // output column
    int rg = tid >> 5;            // row group 0..15
    int r0 = rg << 3;             // first of 8 consecutive output rows
    int ht = tid >> 2;            // hblur row lane 0..127
    int hg = (tid & 3) << 3;      // hblur col group {0,8,16,24}
    bool edgeX = (tx < 2) || (tx > 29);

    // ---- per-pixel bins (inline, pure integer) ----
    const int* f = fix + (bc / 3) * 6;
    int fy0 = f[0], fx0 = f[1], fy1 = f[2], fx1 = f[3], fy2 = f[4], fx2 = f[5];
    int T[16];
#pragma unroll
    for (int q = 1; q < 16; q++) T[q] = thr[q];
    int xk = x0 + c;
    int dx0 = (xk - fx0) * (xk - fx0);
    int dx1 = (xk - fx1) * (xk - fx1);
    int dx2 = (xk - fx2) * (xk - fx2);
    unsigned int mybLo = 0, mybHi = 0, m = 0;
#pragma unroll
    for (int r = 0; r < 8; r++) {
        int yk = y0 + r0 + r;
        int e0 = dx0 + (yk - fy0) * (yk - fy0);
        int e1 = dx1 + (yk - fy1) * (yk - fy1);
        int e2 = dx2 + (yk - fy2) * (yk - fy2);
        int d2 = min(e0, min(e1, e2));
        unsigned int bin = 0;
#pragma unroll
        for (int q = 1; q < 16; q++) bin += (d2 >= T[q]) ? 1u : 0u;
        if (r < 4) mybLo |= bin << (r * 8); else mybHi |= bin << ((r - 4) * 8);
        m |= 1u << bin;
    }
    tmask[tid] = m;
    __syncthreads();
    if (tid < 16) {                       // per-rowgroup bin mask
        unsigned int a = 0;
        for (int i = 0; i < 32; i++) a |= tmask[tid * 32 + i];
        gm[tid] = a;
    }
    __syncthreads();
    if (tid < 16) {                       // per-bin rowgroup mask
        unsigned int br = 0;
        for (int g = 0; g < 16; g++) br |= ((gm[g] >> tid) & 1u) << g;
        binrows[tid] = br;
    }
    __syncthreads();
    unsigned int mask = 0;
    for (int q = 0; q < 16; q++) mask |= (binrows[q] ? 1u : 0u) << q;

    float accOut[8];
#pragma unroll
    for (int i = 0; i < 8; i++) accOut[i] = 0.f;

    while (mask) {
        int q = __builtin_ffs((int)mask) - 1;
        mask &= mask - 1;
        q = __builtin_amdgcn_readfirstlane(q);
        unsigned int br = __builtin_amdgcn_readfirstlane(binrows[q]);
        int g0 = __builtin_ffs((int)br) - 1;
        int g1 = 31 - __builtin_clz(br);
        int R = (9 * q + 4) >> 2;
        int ks = 2 * R + 1;
        int lead = (-R) & 3;
        int ksEh = (lead + ks + 3) & ~3;
        int rbase = g0 << 3;
        int rend  = (g1 << 3) + 8 + 2 * R;     // exclusive; <= 196
        const float* wh  = wtabH + q * 72;
        const float* wvp = wtabV + q * 88;

        if (q == 15) hblur_pass<72>(xp, hbuf, wh, x0, y0, rbase, rend, R, lead, ksEh, ht, hg, edgeX);
        else         hblur_pass<0>(xp, hbuf, wh, x0, y0, rbase, rend, R, lead, ksEh, ht, hg, edgeX);
        __syncthreads();

        if ((br >> rg) & 1u) {
            float a[8] = {0.f, 0.f, 0.f, 0.f, 0.f, 0.f, 0.f, 0.f};
            const float* hb = &hbuf[r0 * HSTRIDE + c];
            if (q == 15) vblur_pass<76>(hb, wvp, 0, a);
            else         vblur_pass<0>(hb, wvp, ks + 7, a);
#pragma unroll
            for (int r = 0; r < 8; r++) {
                unsigned int b = (r < 4 ? mybLo >> (r * 8) : mybHi >> ((r - 4) * 8)) & 255u;
                if ((int)b == q) accOut[r] = a[r];
            }
        }
        __syncthreads();
    }

#pragma unroll
    for (int r = 0; r < 8; r++)
        op[((size_t)(y0 + r0 + r) << 10) + x0 + c] = accOut[r];
}

extern "C" void kernel_launch(void* const* d_in, const int* in_sizes, int n_in,
                              void* d_out, int out_size, void* d_ws, size_t ws_size,
                              hipStream_t stream) {
    const float* x = (const float*)d_in[0];
    const int* fix = (const int*)d_in[1];
    float* out = (float*)d_out;

    float* wtabH = (float*)d_ws;                       // 16*72*4 = 4608 B
    float* wtabV = (float*)((char*)d_ws + 4608);       // 16*88*4 = 5632 B
    int* thr = (int*)((char*)d_ws + 10240);            // 64 B

    hipLaunchKernelGGL(precompute_kernel, dim3(1), dim3(64), 0, stream, wtabH, wtabV, thr);
    hipLaunchKernelGGL(tile_kernel, dim3(6144), dim3(512), 0, stream,
                       x, fix, thr, wtabH, wtabV, out);
}

// Round 7
// 579.269 us; speedup vs baseline: 1.8263x; 1.8263x over previous
//
#include <hip/hip_runtime.h>

// FAPBlur: foveated adaptive gaussian blur.
// bin(p) via integer d^2 thresholds (monotone map d2 -> sigma -> bin).
// Per 32x128 tile: loop over bins present, restricted to the row-groups that
// contain each bin: hblur (global->LDS) then vblur (LDS->regs), masked merge.
// R7: chunked (#pragma unroll 1) blur loops with small live sets -- fixes the
// R6 scratch-spill (WRITE 1.16GB, VALUBusy 24%) caused by full unrolls under
// the 128-VGPR cap. One runtime path, no q==15 templates.

#define TW 32
#define TH 128
#define HSTRIDE 36             // 36 mod 32 = 4 -> bank spread
#define HROWS 196              // TH + 2*RMAX (RMAX=34)

// ---------------- kernel 0: thresholds + gaussian weight tables ----------------
__global__ void precompute_kernel(float* __restrict__ wtabH, float* __restrict__ wtabV,
                                  int* __restrict__ thr) {
    int t = threadIdx.x;
    if (t >= 1 && t < 16) {
        // minimal integer d2 with sigma_px(d2) > 0.75*t  (weakly monotone)
        float edge = 0.75f * (float)t;
        int lo = 0, hi = 2093059;
        while (lo < hi) {
            int mid = (lo + hi) >> 1;
            float d  = sqrtf((float)mid);
            float dm = d * 0.07f;              // PIXEL_MM
            float a  = 1.5f * (dm - 18.2f);    // ALPHA*(d_mm - MU)
            double p = 1.0 / (1.0 + exp((double)(-a)));
            float sm = 0.84f * (float)p;       // BETA
            float v  = fminf(fmaxf(sm / 0.07f, 0.0f), 12.0f);
            if (v > edge) hi = mid; else lo = mid + 1;
        }
        thr[t] = lo;
    }
    if (t >= 32 && t < 48) {
        int q = t - 32;
        double s = 0.75 * ((double)q + 0.5);
        int R = (9 * q + 4) >> 2;              // == int(3*s)
        int ks = 2 * R + 1;
        int lead = (-R) & 3;
        double sum = 0.0;
        for (int j = 0; j < ks; j++) {
            double ax = (double)(j - R);
            sum += exp(-0.5 * (ax / s) * (ax / s));
        }
        for (int jj = 0; jj < 72; jj++) {
            int j = jj - lead;
            float w = 0.f;
            if (j >= 0 && j < ks) {
                double ax = (double)(j - R);
                w = (float)(exp(-0.5 * (ax / s) * (ax / s)) / sum);
            }
            wtabH[q * 72 + jj] = w;            // lead-shifted for aligned float4
        }
        for (int jj = 0; jj < 88; jj++) {
            int j = jj - 7;
            float w = 0.f;
            if (j >= 0 && j < ks) {
                double ax = (double)(j - R);
                w = (float)(exp(-0.5 * (ax / s) * (ax / s)) / sum);
            }
            wtabV[q * 88 + jj] = w;            // 7-lead pad: wvp[7+s-r] always valid
        }
    }
}

// ---------------- hblur step: 8 cols advance 4 taps ----------------
#define HB_STEP(jb_) { \
    float4 wq = *(const float4*)(wh + (jb_)); \
    float4 q2 = L4(A + (jb_) + 8); \
    a0 += wq.x*q0.x + wq.y*q0.y + wq.z*q0.z + wq.w*q0.w; \
    a1 += wq.x*q0.y + wq.y*q0.z + wq.z*q0.w + wq.w*q1.x; \
    a2 += wq.x*q0.z + wq.y*q0.w + wq.z*q1.x + wq.w*q1.y; \
    a3 += wq.x*q0.w + wq.y*q1.x + wq.z*q1.y + wq.w*q1.z; \
    a4 += wq.x*q1.x + wq.y*q1.y + wq.z*q1.z + wq.w*q1.w; \
    a5 += wq.x*q1.y + wq.y*q1.z + wq.z*q1.w + wq.w*q2.x; \
    a6 += wq.x*q1.z + wq.y*q1.w + wq.z*q2.x + wq.w*q2.y; \
    a7 += wq.x*q1.w + wq.y*q2.x + wq.z*q2.y + wq.w*q2.z; \
    q0 = q1; q1 = q2; }

template<bool EDGE>
__device__ __forceinline__ void hblur_row(const float* __restrict__ xr, float* hd,
                                          const float* __restrict__ wh, int A, int ksE8) {
    auto L4 = [&](int idx) -> float4 {
        if constexpr (EDGE) {
            bool v = (unsigned)idx < 1021u;      // aligned float4 fully in [0,1024)
            const float* p = xr + (v ? idx : 0);
            float4 r = *(const float4*)p;
            if (!v) { r.x = 0.f; r.y = 0.f; r.z = 0.f; r.w = 0.f; }
            return r;
        } else {
            return *(const float4*)(xr + idx);
        }
    };
    float a0 = 0.f, a1 = 0.f, a2 = 0.f, a3 = 0.f, a4 = 0.f, a5 = 0.f, a6 = 0.f, a7 = 0.f;
    float4 q0 = L4(A), q1 = L4(A + 4);
#pragma unroll 1
    for (int jb = 0; jb < ksE8; jb += 8) {       // 8-tap chunks: small live set
        HB_STEP(jb)
        HB_STEP(jb + 4)
    }
    *(float4*)hd       = make_float4(a0, a1, a2, a3);
    *(float4*)(hd + 4) = make_float4(a4, a5, a6, a7);
}

// ---------------- vblur body: one hbuf row feeds 8 outputs ----------------
#define VB_BODY(s_) { \
    float v = hb[(s_) * HSTRIDE]; \
    a[0] += wvp[7 + (s_)] * v; \
    a[1] += wvp[6 + (s_)] * v; \
    a[2] += wvp[5 + (s_)] * v; \
    a[3] += wvp[4 + (s_)] * v; \
    a[4] += wvp[3 + (s_)] * v; \
    a[5] += wvp[2 + (s_)] * v; \
    a[6] += wvp[1 + (s_)] * v; \
    a[7] += wvp[0 + (s_)] * v; }

// ---------------- main tile kernel ----------------
__global__ __launch_bounds__(512, 4) void tile_kernel(const float* __restrict__ x,
                                                      const int* __restrict__ fix,
                                                      const int* __restrict__ thr,
                                                      const float* __restrict__ wtabH,
                                                      const float* __restrict__ wtabV,
                                                      float* __restrict__ out) {
    __shared__ __align__(16) float hbuf[HROWS * HSTRIDE];  // 28,224 B
    __shared__ unsigned int tmask[512];
    __shared__ unsigned int gm[16];
    __shared__ unsigned int binrows[16];

    int blk = blockIdx.x;
    int swz = (blk & 7) * 768 + (blk >> 3);   // XCD-contiguous chunks (6144 = 8*768)
    int tx = swz & 31;
    int ty = (swz >> 5) & 7;
    int bc = swz >> 8;                        // 0..23 = b*3 + ch
    const size_t plane = (size_t)bc << 20;
    const float* xp = x + plane;
    float* op = out + plane;
    int x0 = tx << 5, y0 = ty << 7;
    int tid = threadIdx.x;

    int c  = tid & 31;            // output column
    int rg = tid >> 5;            // row group 0..15
    int r0 = rg << 3;             // first of 8 consecutive output rows
    int ht = tid >> 2;            // hblur row lane 0..127
    int hg = (tid & 3) << 3;      // hblur col group {0,8,16,24}
    bool edgeX = (tx < 2) || (tx > 29);

    // ---- per-pixel bins (inline, pure integer) ----
    const int* f = fix + (bc / 3) * 6;
    int fy0 = f[0], fx0 = f[1], fy1 = f[2], fx1 = f[3], fy2 = f[4], fx2 = f[5];
    int T[16];
#pragma unroll
    for (int q = 1; q < 16; q++) T[q] = thr[q];
    int xk = x0 + c;
    int dx0 = (xk - fx0) * (xk - fx0);
    int dx1 = (xk - fx1) * (xk - fx1);
    int dx2 = (xk - fx2) * (xk - fx2);
    unsigned int mybLo = 0, mybHi = 0, m = 0;
#pragma unroll
    for (int r = 0; r < 8; r++) {
        int yk = y0 + r0 + r;
        int e0 = dx0 + (yk - fy0) * (yk - fy0);
        int e1 = dx1 + (yk - fy1) * (yk - fy1);
        int e2 = dx2 + (yk - fy2) * (yk - fy2);
        int d2 = min(e0, min(e1, e2));
        unsigned int bin = 0;
#pragma unroll
        for (int q = 1; q < 16; q++) bin += (d2 >= T[q]) ? 1u : 0u;
        if (r < 4) mybLo |= bin << (r * 8); else mybHi |= bin << ((r - 4) * 8);
        m |= 1u << bin;
    }
    tmask[tid] = m;
    __syncthreads();
    if (tid < 16) {                       // per-rowgroup bin mask
        unsigned int a = 0;
        for (int i = 0; i < 32; i++) a |= tmask[tid * 32 + i];
        gm[tid] = a;
    }
    __syncthreads();
    if (tid < 16) {                       // per-bin rowgroup mask
        unsigned int br = 0;
        for (int g = 0; g < 16; g++) br |= ((gm[g] >> tid) & 1u) << g;
        binrows[tid] = br;
    }
    __syncthreads();
    unsigned int mask = 0;
    for (int q = 0; q < 16; q++) mask |= (binrows[q] ? 1u : 0u) << q;

    float accOut[8];
#pragma unroll
    for (int i = 0; i < 8; i++) accOut[i] = 0.f;

    while (mask) {
        int q = __builtin_ffs((int)mask) - 1;
        mask &= mask - 1;
        q = __builtin_amdgcn_readfirstlane(q);
        unsigned int br = __builtin_amdgcn_readfirstlane(binrows[q]);
        int g0 = __builtin_ffs((int)br) - 1;
        int g1 = 31 - __builtin_clz(br);
        int R = (9 * q + 4) >> 2;
        int ks = 2 * R + 1;
        int lead = (-R) & 3;
        int ksE8 = (lead + ks + 7) & ~7;       // <= 72 (8-tap chunks; table 0-padded)
        int nsE  = (ks + 7 + 3) & ~3;          // vblur rows, 4-row chunks
        int rbase = g0 << 3;
        int rend  = (g1 << 3) + 8 + 2 * R + 2; // +2: chunk-padded vblur reads
        if (rend > HROWS) rend = HROWS;
        const float* wh  = wtabH + q * 72;
        const float* wvp = wtabV + q * 88;

        // ---- horizontal: hbuf[h][cg] = sum_j w[j] x[y0+h-R][x0+cg+j-R]
        for (int h = rbase + ht; h < rend; h += 128) {
            int gy = y0 + h - R;
            float* hd = &hbuf[h * HSTRIDE + hg];
            if ((unsigned)gy < 1024u) {
                const float* xr = xp + ((size_t)gy << 10);
                int A = x0 + hg - R - lead;    // 4-aligned
                if (edgeX) hblur_row<true>(xr, hd, wh, A, ksE8);
                else       hblur_row<false>(xr, hd, wh, A, ksE8);
            } else {
                *(float4*)hd       = make_float4(0.f, 0.f, 0.f, 0.f);
                *(float4*)(hd + 4) = make_float4(0.f, 0.f, 0.f, 0.f);
            }
        }
        __syncthreads();

        // ---- vertical: out[r] = sum_s wvp[7+s-r] * hbuf[r0+s][c]
        if ((br >> rg) & 1u) {
            float a[8] = {0.f, 0.f, 0.f, 0.f, 0.f, 0.f, 0.f, 0.f};
            const float* hb = &hbuf[r0 * HSTRIDE + c];
#pragma unroll 1
            for (int s = 0; s < nsE; s += 4) { // 4-row chunks: 11 weights live
                VB_BODY(s)
                VB_BODY(s + 1)
                VB_BODY(s + 2)
                VB_BODY(s + 3)
            }
#pragma unroll
            for (int r = 0; r < 8; r++) {
                unsigned int b = (r < 4 ? mybLo >> (r * 8) : mybHi >> ((r - 4) * 8)) & 255u;
                if ((int)b == q) accOut[r] = a[r];
            }
        }
        __syncthreads();
    }

#pragma unroll
    for (int r = 0; r < 8; r++)
        op[((size_t)(y0 + r0 + r) << 10) + x0 + c] = accOut[r];
}

extern "C" void kernel_launch(void* const* d_in, const int* in_sizes, int n_in,
                              void* d_out, int out_size, void* d_ws, size_t ws_size,
                              hipStream_t stream) {
    const float* x = (const float*)d_in[0];
    const int* fix = (const int*)d_in[1];
    float* out = (float*)d_out;

    float* wtabH = (float*)d_ws;                       // 16*72*4 = 4608 B
    float* wtabV = (float*)((char*)d_ws + 4608);       // 16*88*4 = 5632 B
    int* thr = (int*)((char*)d_ws + 10240);            // 64 B

    hipLaunchKernelGGL(precompute_kernel, dim3(1), dim3(64), 0, stream, wtabH, wtabV, thr);
    hipLaunchKernelGGL(tile_kernel, dim3(6144), dim3(512), 0, stream,
                       x, fix, thr, wtabH, wtabV, out);
}